// Round 1
// baseline (188.053 us; speedup 1.0000x reference)
//
#include <hip/hip_runtime.h>
#include <math.h>

#define H 2400
#define W 2400
#define SX 30
#define SY 30
#define NBX 80
#define NBY 80
#define NBLK (NBX * NBY)
#define GCOEF 0.5f
#define PI_F 3.14159265358979323846f

// Monotone float -> uint mapping so atomicMax on uint orders like float.
__device__ __forceinline__ unsigned int fmap(float f) {
    unsigned int u = __float_as_uint(f);
    return (u & 0x80000000u) ? ~u : (u | 0x80000000u);
}
__device__ __forceinline__ float funmap(unsigned int u) {
    return (u & 0x80000000u) ? __uint_as_float(u & 0x7fffffffu)
                             : __uint_as_float(~u);
}

// One workgroup per 30x30 block. Reduces the 7 quantities the BRF actually
// needs (te[2..6,8,9] and f_edge are dead code in the reference) plus the
// tile max of CHM (for the global CHM.max()).
__global__ __launch_bounds__(256) void block_stats(
    const float* __restrict__ chm,
    const float* __restrict__ th,
    const float* __restrict__ favd,
    const float* __restrict__ sza,
    float* __restrict__ sums,          // [7][NBLK]
    unsigned int* __restrict__ gmax)   // ordered-uint global max
{
    __shared__ float tile[32][33];     // 30x30 tile + 1-px halo, padded stride
    __shared__ float red[4][8];

    const int blk = blockIdx.x;
    const int bx = blk / NBY, by = blk % NBY;
    const int gi0 = bx * SX, gj0 = by * SY;
    const int tid = threadIdx.x;

    // Stage halo tile (out-of-image -> 0; those values are never used because
    // edge is forced 0 on non-interior pixels).
    for (int idx = tid; idx < 32 * 32; idx += 256) {
        int r = idx >> 5, c = idx & 31;
        int gi = gi0 - 1 + r, gj = gj0 - 1 + c;
        float v = 0.0f;
        if (gi >= 0 && gi < H && gj >= 0 && gj < W) v = chm[gi * W + gj];
        tile[r][c] = v;
    }
    __syncthreads();

    const float th_b   = th[blk];
    const float favd_b = favd[blk];
    const float sza_b  = sza[blk];
    const float a      = -GCOEF * favd_b;
    const float mu     = fmaxf(cosf(sza_b * (PI_F / 180.0f)), 1e-3f);
    const float inv_mu = 1.0f / mu;

    float s_mask = 0.f, s_edge = 0.f, s_gs = 0.f, s_gv = 0.f;
    float s_chm = 0.f, s_egs = 0.f, s_mgv = 0.f;
    float vmax = -INFINITY;

    for (int idx = tid; idx < SX * SY; idx += 256) {
        int li = idx / SY, lj = idx - li * SY;
        int r = li + 1, c = lj + 1;
        float center = tile[r][c];
        bool  m = center > 0.0f;
        int gi = gi0 + li, gj = gj0 + lj;
        int ns = 0;
        ns += (tile[r - 1][c - 1] > 0.f);
        ns += (tile[r - 1][c    ] > 0.f);
        ns += (tile[r - 1][c + 1] > 0.f);
        ns += (tile[r    ][c - 1] > 0.f);
        ns += (tile[r    ][c + 1] > 0.f);
        ns += (tile[r + 1][c - 1] > 0.f);
        ns += (tile[r + 1][c    ] > 0.f);
        ns += (tile[r + 1][c + 1] > 0.f);
        bool interior = (gi >= 1) & (gi <= H - 2) & (gj >= 1) & (gj <= W - 2);
        float edge = (m && interior && (ns <= 6)) ? 1.0f : 0.0f;

        float crown    = fmaxf(center - th_b, 0.0f);
        float gap_view = __expf(a * crown);
        float gap_sun  = __expf(a * crown * inv_mu);
        float fm = m ? 1.0f : 0.0f;

        s_mask += fm;
        s_edge += edge;
        s_gs   += gap_sun;
        s_gv   += gap_view;
        s_chm  += center;
        s_egs  += edge * gap_sun;
        s_mgv  += fm * gap_view;
        vmax = fmaxf(vmax, center);
    }

    // wave64 shuffle reduce, then cross-wave via LDS
    for (int off = 32; off >= 1; off >>= 1) {
        s_mask += __shfl_down(s_mask, off, 64);
        s_edge += __shfl_down(s_edge, off, 64);
        s_gs   += __shfl_down(s_gs,   off, 64);
        s_gv   += __shfl_down(s_gv,   off, 64);
        s_chm  += __shfl_down(s_chm,  off, 64);
        s_egs  += __shfl_down(s_egs,  off, 64);
        s_mgv  += __shfl_down(s_mgv,  off, 64);
        vmax = fmaxf(vmax, __shfl_down(vmax, off, 64));
    }
    int wid = tid >> 6, lane = tid & 63;
    if (lane == 0) {
        red[wid][0] = s_mask; red[wid][1] = s_edge; red[wid][2] = s_gs;
        red[wid][3] = s_gv;   red[wid][4] = s_chm;  red[wid][5] = s_egs;
        red[wid][6] = s_mgv;  red[wid][7] = vmax;
    }
    __syncthreads();
    if (tid == 0) {
        float t0 = 0, t1 = 0, t2 = 0, t3 = 0, t4 = 0, t5 = 0, t6 = 0;
        float tm = -INFINITY;
        for (int w2 = 0; w2 < 4; ++w2) {
            t0 += red[w2][0]; t1 += red[w2][1]; t2 += red[w2][2];
            t3 += red[w2][3]; t4 += red[w2][4]; t5 += red[w2][5];
            t6 += red[w2][6];
            tm = fmaxf(tm, red[w2][7]);
        }
        sums[0 * NBLK + blk] = t0;
        sums[1 * NBLK + blk] = t1;
        sums[2 * NBLK + blk] = t2;
        sums[3 * NBLK + blk] = t3;
        sums[4 * NBLK + blk] = t4;
        sums[5 * NBLK + blk] = t5;
        sums[6 * NBLK + blk] = t6;
        atomicMax(gmax, fmap(tm));
    }
}

__global__ __launch_bounds__(256) void finalize(
    const float* __restrict__ sums,
    const unsigned int* __restrict__ gmax,
    const float* __restrict__ saa,
    const float* __restrict__ rl,
    const float* __restrict__ tl,
    const float* __restrict__ rs,
    const float* __restrict__ belta,
    float* __restrict__ out)
{
    int b = blockIdx.x * blockDim.x + threadIdx.x;
    if (b >= NBLK) return;
    const float invN = 1.0f / 900.0f;

    float s_mask = sums[0 * NBLK + b];
    float s_edge = sums[1 * NBLK + b];
    float te0  = sums[2 * NBLK + b] * invN;   // mean gap_sun
    float te1  = sums[3 * NBLK + b] * invN;   // mean gap_view
    float s_chm = sums[4 * NBLK + b];
    float te11 = sums[5 * NBLK + b] * invN;   // mean edge*gap_sun
    float te12 = sums[6 * NBLK + b] * invN;   // mean mask*gap_view

    float chm_max = funmap(*gmax);
    float te10 = s_chm * invN / chm_max;      // mean rel_h
    float te7  = s_edge * invN;               // mean edge
    // gap_count = #gap + 0.5*#edge ; #gap = 900 - #mask
    float f_gap = ((900.0f - s_mask) + 0.5f * s_edge) * invN;

    float Pgs   = te0;
    float Pboth = te0 * te1;
    float Kg = f_gap * Pgs;
    float Kz = f_gap * (1.0f - Pgs);
    float Kc = (1.0f - f_gap) * Pboth;
    float Kt = fmaxf((1.0f - f_gap) - Kc, 0.0f);
    float hot = 1.0f + 0.1f * cosf(saa[b] * (PI_F / 180.0f));

    float brf = (rl[b] * Kc + tl[b] * belta[b] * Kt + rs[b] * Kg
               + rs[b] * belta[b] * Kz + rl[b] * te7 * te10
               + tl[b] * (1.0f - belta[b]) * te11
               + rs[b] * te12 * f_gap) * hot;

    out[0 * NBLK + b] = brf;
    out[1 * NBLK + b] = brf;
    out[2 * NBLK + b] = brf;
    out[3 * NBLK + b] = brf;
}

extern "C" void kernel_launch(void* const* d_in, const int* in_sizes, int n_in,
                              void* d_out, int out_size, void* d_ws, size_t ws_size,
                              hipStream_t stream) {
    const float* chm   = (const float*)d_in[0];
    // d_in[1] = PATH1, d_in[2] = PATH2 — dead code in the reference's output
    const float* th    = (const float*)d_in[3];
    const float* favd  = (const float*)d_in[4];
    const float* sza   = (const float*)d_in[5];
    const float* saa   = (const float*)d_in[6];
    const float* rl    = (const float*)d_in[7];
    const float* tl    = (const float*)d_in[8];
    const float* rs    = (const float*)d_in[9];
    const float* belta = (const float*)d_in[10];
    float* out = (float*)d_out;

    float* sums = (float*)d_ws;                                    // 7*NBLK floats
    unsigned int* gmax = (unsigned int*)((char*)d_ws + 7 * NBLK * sizeof(float));

    hipMemsetAsync(gmax, 0, sizeof(unsigned int), stream);
    block_stats<<<NBLK, 256, 0, stream>>>(chm, th, favd, sza, sums, gmax);
    finalize<<<(NBLK + 255) / 256, 256, 0, stream>>>(sums, gmax, saa, rl, tl, rs, belta, out);
}

// Round 2
// 136.036 us; speedup vs baseline: 1.3824x; 1.3824x over previous
//
#include <hip/hip_runtime.h>
#include <math.h>

#define H 2400
#define W 2400
#define SX 30
#define SY 30
#define NBX 80
#define NBY 80
#define NBLK (NBX * NBY)
#define GCOEF 0.5f
#define PI_F 3.14159265358979323846f

// One workgroup per 30x30 block. Reduces the 7 quantities the BRF actually
// needs (te[2..6,8,9] and f_edge are dead code in the reference) plus the
// tile max of CHM. NO global atomics: per-block max goes to sums[7][blk];
// finalize_all computes the global max (removes the 6400-way single-address
// atomic serialization that made R1's block_stats latency-bound at 83 us).
__global__ __launch_bounds__(256) void block_stats(
    const float* __restrict__ chm,
    const float* __restrict__ th,
    const float* __restrict__ favd,
    const float* __restrict__ sza,
    float* __restrict__ sums)          // [8][NBLK]
{
    __shared__ float tile[32][33];     // 30x30 tile + 1-px halo, padded stride
    __shared__ float red[4][8];

    const int blk = blockIdx.x;
    const int bx = blk / NBY, by = blk % NBY;
    const int gi0 = bx * SX, gj0 = by * SY;
    const int tid = threadIdx.x;

    // Stage halo tile (out-of-image -> 0; those values are never used because
    // edge is forced 0 on non-interior pixels).
    for (int idx = tid; idx < 32 * 32; idx += 256) {
        int r = idx >> 5, c = idx & 31;
        int gi = gi0 - 1 + r, gj = gj0 - 1 + c;
        float v = 0.0f;
        if (gi >= 0 && gi < H && gj >= 0 && gj < W) v = chm[gi * W + gj];
        tile[r][c] = v;
    }
    __syncthreads();

    const float th_b   = th[blk];
    const float favd_b = favd[blk];
    const float sza_b  = sza[blk];
    const float a      = -GCOEF * favd_b;
    const float mu     = fmaxf(cosf(sza_b * (PI_F / 180.0f)), 1e-3f);
    const float inv_mu = 1.0f / mu;

    float s_mask = 0.f, s_edge = 0.f, s_gs = 0.f, s_gv = 0.f;
    float s_chm = 0.f, s_egs = 0.f, s_mgv = 0.f;
    float vmax = -INFINITY;

    for (int idx = tid; idx < SX * SY; idx += 256) {
        int li = idx / SY, lj = idx - li * SY;
        int r = li + 1, c = lj + 1;
        float center = tile[r][c];
        bool  m = center > 0.0f;
        int gi = gi0 + li, gj = gj0 + lj;
        int ns = 0;
        ns += (tile[r - 1][c - 1] > 0.f);
        ns += (tile[r - 1][c    ] > 0.f);
        ns += (tile[r - 1][c + 1] > 0.f);
        ns += (tile[r    ][c - 1] > 0.f);
        ns += (tile[r    ][c + 1] > 0.f);
        ns += (tile[r + 1][c - 1] > 0.f);
        ns += (tile[r + 1][c    ] > 0.f);
        ns += (tile[r + 1][c + 1] > 0.f);
        bool interior = (gi >= 1) & (gi <= H - 2) & (gj >= 1) & (gj <= W - 2);
        float edge = (m && interior && (ns <= 6)) ? 1.0f : 0.0f;

        float crown    = fmaxf(center - th_b, 0.0f);
        float gap_view = __expf(a * crown);
        float gap_sun  = __expf(a * crown * inv_mu);
        float fm = m ? 1.0f : 0.0f;

        s_mask += fm;
        s_edge += edge;
        s_gs   += gap_sun;
        s_gv   += gap_view;
        s_chm  += center;
        s_egs  += edge * gap_sun;
        s_mgv  += fm * gap_view;
        vmax = fmaxf(vmax, center);
    }

    // wave64 shuffle reduce, then cross-wave via LDS
    for (int off = 32; off >= 1; off >>= 1) {
        s_mask += __shfl_down(s_mask, off, 64);
        s_edge += __shfl_down(s_edge, off, 64);
        s_gs   += __shfl_down(s_gs,   off, 64);
        s_gv   += __shfl_down(s_gv,   off, 64);
        s_chm  += __shfl_down(s_chm,  off, 64);
        s_egs  += __shfl_down(s_egs,  off, 64);
        s_mgv  += __shfl_down(s_mgv,  off, 64);
        vmax = fmaxf(vmax, __shfl_down(vmax, off, 64));
    }
    int wid = tid >> 6, lane = tid & 63;
    if (lane == 0) {
        red[wid][0] = s_mask; red[wid][1] = s_edge; red[wid][2] = s_gs;
        red[wid][3] = s_gv;   red[wid][4] = s_chm;  red[wid][5] = s_egs;
        red[wid][6] = s_mgv;  red[wid][7] = vmax;
    }
    __syncthreads();
    if (tid < 8) {
        // 8 threads, one per quantity: gather the 4 wave partials
        float t;
        if (tid == 7) {
            t = fmaxf(fmaxf(red[0][7], red[1][7]), fmaxf(red[2][7], red[3][7]));
        } else {
            t = red[0][tid] + red[1][tid] + red[2][tid] + red[3][tid];
        }
        sums[tid * NBLK + blk] = t;
    }
}

// Single workgroup: global max over per-block maxes, then all 6400 BRF values.
__global__ __launch_bounds__(1024) void finalize_all(
    const float* __restrict__ sums,    // [8][NBLK]
    const float* __restrict__ saa,
    const float* __restrict__ rl,
    const float* __restrict__ tl,
    const float* __restrict__ rs,
    const float* __restrict__ belta,
    float* __restrict__ out)
{
    __shared__ float smax[16];
    const int tid = threadIdx.x;

    float m = -INFINITY;
    for (int b = tid; b < NBLK; b += 1024) m = fmaxf(m, sums[7 * NBLK + b]);
    for (int off = 32; off >= 1; off >>= 1) m = fmaxf(m, __shfl_down(m, off, 64));
    int wid = tid >> 6, lane = tid & 63;
    if (lane == 0) smax[wid] = m;
    __syncthreads();
    if (tid == 0) {
        float t = smax[0];
        for (int w2 = 1; w2 < 16; ++w2) t = fmaxf(t, smax[w2]);
        smax[0] = t;
    }
    __syncthreads();
    const float inv_max = 1.0f / smax[0];
    const float invN = 1.0f / 900.0f;

    for (int b = tid; b < NBLK; b += 1024) {
        float s_mask = sums[0 * NBLK + b];
        float s_edge = sums[1 * NBLK + b];
        float te0  = sums[2 * NBLK + b] * invN;   // mean gap_sun
        float te1  = sums[3 * NBLK + b] * invN;   // mean gap_view
        float s_chm = sums[4 * NBLK + b];
        float te11 = sums[5 * NBLK + b] * invN;   // mean edge*gap_sun
        float te12 = sums[6 * NBLK + b] * invN;   // mean mask*gap_view

        float te10 = s_chm * invN * inv_max;      // mean rel_h
        float te7  = s_edge * invN;               // mean edge
        // gap_count = #gap + 0.5*#edge ; #gap = 900 - #mask
        float f_gap = ((900.0f - s_mask) + 0.5f * s_edge) * invN;

        float Pgs   = te0;
        float Pboth = te0 * te1;
        float Kg = f_gap * Pgs;
        float Kz = f_gap * (1.0f - Pgs);
        float Kc = (1.0f - f_gap) * Pboth;
        float Kt = fmaxf((1.0f - f_gap) - Kc, 0.0f);
        float hot = 1.0f + 0.1f * cosf(saa[b] * (PI_F / 180.0f));

        float brf = (rl[b] * Kc + tl[b] * belta[b] * Kt + rs[b] * Kg
                   + rs[b] * belta[b] * Kz + rl[b] * te7 * te10
                   + tl[b] * (1.0f - belta[b]) * te11
                   + rs[b] * te12 * f_gap) * hot;

        out[0 * NBLK + b] = brf;
        out[1 * NBLK + b] = brf;
        out[2 * NBLK + b] = brf;
        out[3 * NBLK + b] = brf;
    }
}

extern "C" void kernel_launch(void* const* d_in, const int* in_sizes, int n_in,
                              void* d_out, int out_size, void* d_ws, size_t ws_size,
                              hipStream_t stream) {
    const float* chm   = (const float*)d_in[0];
    // d_in[1] = PATH1, d_in[2] = PATH2 — dead code in the reference's output
    const float* th    = (const float*)d_in[3];
    const float* favd  = (const float*)d_in[4];
    const float* sza   = (const float*)d_in[5];
    const float* saa   = (const float*)d_in[6];
    const float* rl    = (const float*)d_in[7];
    const float* tl    = (const float*)d_in[8];
    const float* rs    = (const float*)d_in[9];
    const float* belta = (const float*)d_in[10];
    float* out = (float*)d_out;

    float* sums = (float*)d_ws;   // [8][NBLK] floats

    block_stats<<<NBLK, 256, 0, stream>>>(chm, th, favd, sza, sums);
    finalize_all<<<1, 1024, 0, stream>>>(sums, saa, rl, tl, rs, belta, out);
}

// Round 3
// 134.031 us; speedup vs baseline: 1.4030x; 1.0150x over previous
//
#include <hip/hip_runtime.h>
#include <math.h>

#define H 2400
#define W 2400
#define SX 30
#define SY 30
#define NBX 80
#define NBY 80
#define NBLK (NBX * NBY)
#define GCOEF 0.5f
#define PI_F 3.14159265358979323846f

// 4 horizontally-adjacent 30x30 blocks per workgroup; one wave64 per block.
// Single __syncthreads (after tile staging); wave-local shuffle reduction;
// per-block results written as sums[blk][8] (two float4s for finalize).
// TILE: 32 rows x 122 cols (+halo), LDS stride 123 (odd -> conflict-free).
__global__ __launch_bounds__(256) void block_stats(
    const float* __restrict__ chm,
    const float* __restrict__ th,
    const float* __restrict__ favd,
    const float* __restrict__ sza,
    float* __restrict__ sums)          // [NBLK][8]
{
    __shared__ float tile[32 * 123];

    const int bx    = blockIdx.x / (NBY / 4);   // block-row 0..79
    const int bcol4 = blockIdx.x % (NBY / 4);   // group of 4 block-cols 0..19
    const int gi0 = bx * SX;                    // first pixel row of strip
    const int gj0 = bcol4 * (4 * SY);           // first pixel col of strip
    const int tid = threadIdx.x;

    // Stage 32x122 halo tile (rows gi0-1..gi0+30, cols gj0-1..gj0+120).
    for (int idx = tid; idx < 32 * 122; idx += 256) {
        int r = idx / 122, c = idx - r * 122;
        int gi = gi0 - 1 + r, gj = gj0 - 1 + c;
        float v = 0.0f;
        if (gi >= 0 && gi < H && gj >= 0 && gj < W) v = chm[gi * W + gj];
        tile[r * 123 + c] = v;
    }
    __syncthreads();

    const int w    = tid >> 6;          // wave id = which block in the strip
    const int lane = tid & 63;
    const int blk  = bx * NBY + bcol4 * 4 + w;
    const int cw   = w * SY;            // this wave's column offset in tile

    const float th_b   = th[blk];
    const float favd_b = favd[blk];
    const float sza_b  = sza[blk];
    const float a      = -GCOEF * favd_b;
    const float mu     = fmaxf(cosf(sza_b * (PI_F / 180.0f)), 1e-3f);
    const float inv_mu = 1.0f / mu;

    float s_mask = 0.f, s_edge = 0.f, s_gs = 0.f, s_gv = 0.f;
    float s_chm = 0.f, s_egs = 0.f, s_mgv = 0.f;
    float vmax = -INFINITY;

    for (int p = lane; p < SX * SY; p += 64) {
        int li = p / SY, lj = p - li * SY;
        const float* row = &tile[(li + 1) * 123 + cw + lj + 1];
        float center = row[0];
        bool  m = center > 0.0f;
        int ns = 0;
        ns += (row[-124] > 0.f); ns += (row[-123] > 0.f); ns += (row[-122] > 0.f);
        ns += (row[-1]   > 0.f); ns += (row[1]    > 0.f);
        ns += (row[122]  > 0.f); ns += (row[123]  > 0.f); ns += (row[124]  > 0.f);
        int gi = gi0 + li, gj = gj0 + cw + lj;
        bool interior = (gi >= 1) & (gi <= H - 2) & (gj >= 1) & (gj <= W - 2);
        float edge = (m && interior && (ns <= 6)) ? 1.0f : 0.0f;

        float crown    = fmaxf(center - th_b, 0.0f);
        float gap_view = __expf(a * crown);
        float gap_sun  = __expf(a * crown * inv_mu);
        float fm = m ? 1.0f : 0.0f;

        s_mask += fm;
        s_edge += edge;
        s_gs   += gap_sun;
        s_gv   += gap_view;
        s_chm  += center;
        s_egs  += edge * gap_sun;
        s_mgv  += fm * gap_view;
        vmax = fmaxf(vmax, center);
    }

    for (int off = 32; off >= 1; off >>= 1) {
        s_mask += __shfl_down(s_mask, off, 64);
        s_edge += __shfl_down(s_edge, off, 64);
        s_gs   += __shfl_down(s_gs,   off, 64);
        s_gv   += __shfl_down(s_gv,   off, 64);
        s_chm  += __shfl_down(s_chm,  off, 64);
        s_egs  += __shfl_down(s_egs,  off, 64);
        s_mgv  += __shfl_down(s_mgv,  off, 64);
        vmax = fmaxf(vmax, __shfl_down(vmax, off, 64));
    }
    if (lane == 0) {
        float* o = &sums[blk * 8];
        o[0] = s_mask; o[1] = s_edge; o[2] = s_gs;  o[3] = s_gv;
        o[4] = s_chm;  o[5] = s_egs;  o[6] = s_mgv; o[7] = vmax;
    }
}

// Single workgroup: global max over per-block maxes, then all 6400 BRF values.
__global__ __launch_bounds__(1024) void finalize_all(
    const float* __restrict__ sums,    // [NBLK][8]
    const float* __restrict__ saa,
    const float* __restrict__ rl,
    const float* __restrict__ tl,
    const float* __restrict__ rs,
    const float* __restrict__ belta,
    float* __restrict__ out)
{
    __shared__ float smax[16];
    const int tid = threadIdx.x;

    float m = -INFINITY;
    for (int b = tid; b < NBLK; b += 1024) m = fmaxf(m, sums[b * 8 + 7]);
    for (int off = 32; off >= 1; off >>= 1) m = fmaxf(m, __shfl_down(m, off, 64));
    int wid = tid >> 6, lane = tid & 63;
    if (lane == 0) smax[wid] = m;
    __syncthreads();
    if (tid == 0) {
        float t = smax[0];
        for (int w2 = 1; w2 < 16; ++w2) t = fmaxf(t, smax[w2]);
        smax[0] = t;
    }
    __syncthreads();
    const float inv_max = 1.0f / smax[0];
    const float invN = 1.0f / 900.0f;

    for (int b = tid; b < NBLK; b += 1024) {
        float4 lo = *(const float4*)&sums[b * 8];
        float4 hi = *(const float4*)&sums[b * 8 + 4];
        float s_mask = lo.x;
        float s_edge = lo.y;
        float te0  = lo.z * invN;     // mean gap_sun
        float te1  = lo.w * invN;     // mean gap_view
        float s_chm = hi.x;
        float te11 = hi.y * invN;     // mean edge*gap_sun
        float te12 = hi.z * invN;     // mean mask*gap_view

        float te10 = s_chm * invN * inv_max;  // mean rel_h
        float te7  = s_edge * invN;           // mean edge
        float f_gap = ((900.0f - s_mask) + 0.5f * s_edge) * invN;

        float Pgs   = te0;
        float Pboth = te0 * te1;
        float Kg = f_gap * Pgs;
        float Kz = f_gap * (1.0f - Pgs);
        float Kc = (1.0f - f_gap) * Pboth;
        float Kt = fmaxf((1.0f - f_gap) - Kc, 0.0f);
        float hot = 1.0f + 0.1f * cosf(saa[b] * (PI_F / 180.0f));

        float brf = (rl[b] * Kc + tl[b] * belta[b] * Kt + rs[b] * Kg
                   + rs[b] * belta[b] * Kz + rl[b] * te7 * te10
                   + tl[b] * (1.0f - belta[b]) * te11
                   + rs[b] * te12 * f_gap) * hot;

        out[0 * NBLK + b] = brf;
        out[1 * NBLK + b] = brf;
        out[2 * NBLK + b] = brf;
        out[3 * NBLK + b] = brf;
    }
}

extern "C" void kernel_launch(void* const* d_in, const int* in_sizes, int n_in,
                              void* d_out, int out_size, void* d_ws, size_t ws_size,
                              hipStream_t stream) {
    const float* chm   = (const float*)d_in[0];
    // d_in[1] = PATH1, d_in[2] = PATH2 — dead code in the reference's output
    const float* th    = (const float*)d_in[3];
    const float* favd  = (const float*)d_in[4];
    const float* sza   = (const float*)d_in[5];
    const float* saa   = (const float*)d_in[6];
    const float* rl    = (const float*)d_in[7];
    const float* tl    = (const float*)d_in[8];
    const float* rs    = (const float*)d_in[9];
    const float* belta = (const float*)d_in[10];
    float* out = (float*)d_out;

    float* sums = (float*)d_ws;   // [NBLK][8] floats

    block_stats<<<NBX * (NBY / 4), 256, 0, stream>>>(chm, th, favd, sza, sums);
    finalize_all<<<1, 1024, 0, stream>>>(sums, saa, rl, tl, rs, belta, out);
}